// Round 1
// baseline (20427.724 us; speedup 1.0000x reference)
//
#include <hip/hip_runtime.h>
#include <math.h>

#define Hd 1024
#define Ed 512
#define Bv 64
#define Sv 128
#define Tv 64
#define Vv 32000

__device__ __forceinline__ float sigf(float x){ return 1.0f/(1.0f + expf(-x)); }

// zero h/c ping-pong buffers (262144 floats) and out[:,0,:]
__global__ __launch_bounds__(256) void k_init(float* __restrict__ ws, float* __restrict__ out){
  long i = (long)blockIdx.x*256 + threadIdx.x;
  if (i < 262144){ ws[i] = 0.f; }
  else {
    long r = i - 262144;            // 0 .. 64*32000-1
    long m = r / Vv, v = r % Vv;
    out[m*Tv*(long)Vv + v] = 0.f;   // [m][0][v]
  }
}

// Fused LSTM step: gates = emb[token] @ Wih^T + h @ Whh^T + b ; cell -> h_out, c_out
// mode 0: encoder (token = src[m*Sv + t])
// mode 1: decoder (token = t==0 ? trg[m*Tv] : (tf[t]>0 ? trg[m*Tv+t] : token_buf[m]))
// grid (32, 8): blockIdx.x -> 32-col tile of 1024 hidden cols, blockIdx.y -> 8-row m tile
__global__ __launch_bounds__(256) void k_step(
    int mode, int t,
    const int* __restrict__ tok_src,      // src or trg
    const int* __restrict__ tf_mask,
    const int* __restrict__ token_buf,
    const float* __restrict__ emb,
    const float* __restrict__ Wih,        // [4096][512]
    const float* __restrict__ Whh,        // [4096][1024]
    const float* __restrict__ bias,       // [4096]
    const float* __restrict__ h_in, const float* __restrict__ c_in,
    float* __restrict__ h_out, float* __restrict__ c_out)
{
  __shared__ __align__(16) float tile[8*1536];  // per m-row: 512 x | 1024 h
  __shared__ float gbuf[4*8*32];
  __shared__ int toks[8];
  const int tid = threadIdx.x;
  const int m0 = blockIdx.y*8, jh0 = blockIdx.x*32;

  if (tid < 8){
    int m = m0 + tid; int tok;
    if (mode == 0) tok = tok_src[m*Sv + t];
    else {
      if (t == 0) tok = tok_src[m*Tv];
      else tok = (tf_mask[t] > 0) ? tok_src[m*Tv + t] : token_buf[m];
    }
    toks[tid] = tok;
  }
  __syncthreads();

  {
    float4* t4 = (float4*)tile;
    #pragma unroll
    for (int r = 0; r < 12; ++r){
      int f = tid + 256*r;          // 0..3071 float4s
      int row = f / 384, o = f % 384;
      float4 v;
      if (o < 128) v = ((const float4*)(emb + (long)toks[row]*Ed))[o];
      else         v = ((const float4*)(h_in + (long)(m0+row)*Hd))[o-128];
      t4[row*384 + o] = v;
    }
  }
  __syncthreads();

  const int g = tid >> 6, s = tid & 63, jl = s & 31, mg = s >> 5;
  const int col = g*Hd + jh0 + jl;
  const float4* wx = (const float4*)(Wih + (long)col*Ed);
  const float4* wh = (const float4*)(Whh + (long)col*Hd);
  const float4* t4 = (const float4*)tile;
  const int mb = mg*4;
  float b = bias[col];
  float a0=b, a1=b, a2=b, a3=b;

  for (int k = 0; k < 128; ++k){
    float4 w = wx[k];
    float4 v0 = t4[(mb+0)*384 + k];
    float4 v1 = t4[(mb+1)*384 + k];
    float4 v2 = t4[(mb+2)*384 + k];
    float4 v3 = t4[(mb+3)*384 + k];
    a0 += w.x*v0.x + w.y*v0.y + w.z*v0.z + w.w*v0.w;
    a1 += w.x*v1.x + w.y*v1.y + w.z*v1.z + w.w*v1.w;
    a2 += w.x*v2.x + w.y*v2.y + w.z*v2.z + w.w*v2.w;
    a3 += w.x*v3.x + w.y*v3.y + w.z*v3.z + w.w*v3.w;
  }
  for (int k = 0; k < 256; ++k){
    float4 w = wh[k];
    float4 v0 = t4[(mb+0)*384 + 128 + k];
    float4 v1 = t4[(mb+1)*384 + 128 + k];
    float4 v2 = t4[(mb+2)*384 + 128 + k];
    float4 v3 = t4[(mb+3)*384 + 128 + k];
    a0 += w.x*v0.x + w.y*v0.y + w.z*v0.z + w.w*v0.w;
    a1 += w.x*v1.x + w.y*v1.y + w.z*v1.z + w.w*v1.w;
    a2 += w.x*v2.x + w.y*v2.y + w.z*v2.z + w.w*v2.w;
    a3 += w.x*v3.x + w.y*v3.y + w.z*v3.z + w.w*v3.w;
  }

  gbuf[g*256 + (mb+0)*32 + jl] = a0;
  gbuf[g*256 + (mb+1)*32 + jl] = a1;
  gbuf[g*256 + (mb+2)*32 + jl] = a2;
  gbuf[g*256 + (mb+3)*32 + jl] = a3;
  __syncthreads();

  const int ml = tid >> 5, j2 = tid & 31;
  float ig = gbuf[0*256 + ml*32 + j2];
  float fg = gbuf[1*256 + ml*32 + j2];
  float gg = gbuf[2*256 + ml*32 + j2];
  float og = gbuf[3*256 + ml*32 + j2];
  long idx = (long)(m0+ml)*Hd + jh0 + j2;
  float c = c_in[idx];
  float cn = sigf(fg)*c + sigf(ig)*tanhf(gg);
  float hn = sigf(og)*tanhf(cn);
  c_out[idx] = cn;
  h_out[idx] = hn;
}

// logits = h @ Wfc^T + bfc -> out[:, j+1, :]
// grid 1000 blocks: block covers all 64 m, 32 v-cols
__global__ __launch_bounds__(256) void k_fc(
    int j, const float* __restrict__ h, const float* __restrict__ Wfc,
    const float* __restrict__ bfc, float* __restrict__ out)
{
  __shared__ __align__(16) float ht[64*128]; // K-chunk of h
  const int tid = threadIdx.x;
  const int v0 = blockIdx.x*32;
  const int vl = tid & 31, mg = tid >> 5;
  const int v = v0 + vl;
  const float4* wf = (const float4*)(Wfc + (long)v*Hd);
  float acc[8];
  #pragma unroll
  for (int i = 0; i < 8; ++i) acc[i] = 0.f;

  for (int kc = 0; kc < Hd; kc += 128){
    __syncthreads();
    #pragma unroll
    for (int r = 0; r < 8; ++r){
      int f = tid + 256*r;        // 0..2047 float4s
      int row = f >> 5, o = f & 31;
      ((float4*)ht)[row*32 + o] = ((const float4*)(h + (long)row*Hd + kc))[o];
    }
    __syncthreads();
    const int kb = kc >> 2;
    for (int k = 0; k < 32; ++k){
      float4 w = wf[kb + k];
      #pragma unroll
      for (int mi = 0; mi < 8; ++mi){
        float4 hv = ((const float4*)ht)[(mg*8+mi)*32 + k];
        acc[mi] += w.x*hv.x + w.y*hv.y + w.z*hv.z + w.w*hv.w;
      }
    }
  }
  float bb = bfc[v];
  #pragma unroll
  for (int mi = 0; mi < 8; ++mi){
    out[((long)(mg*8+mi)*Tv + (j+1))*(long)Vv + v] = acc[mi] + bb;
  }
}

// first-index argmax over out[m, j+1, :] -> token_buf[m]
__global__ __launch_bounds__(256) void k_argmax(
    int j, const float* __restrict__ out, int* __restrict__ token_buf)
{
  __shared__ float sval[256];
  __shared__ int   sidx[256];
  const int m = blockIdx.x, tid = threadIdx.x;
  const float* base = out + ((long)m*Tv + (j+1))*(long)Vv;
  float best = -INFINITY; int bi = 0;
  for (int v = tid; v < Vv; v += 256){
    float f = base[v];
    if (f > best){ best = f; bi = v; }
  }
  sval[tid] = best; sidx[tid] = bi;
  __syncthreads();
  for (int s2 = 128; s2 > 0; s2 >>= 1){
    if (tid < s2){
      float ov = sval[tid+s2]; int oi = sidx[tid+s2];
      if (ov > sval[tid] || (ov == sval[tid] && oi < sidx[tid])){
        sval[tid] = ov; sidx[tid] = oi;
      }
    }
    __syncthreads();
  }
  if (tid == 0) token_buf[m] = sidx[0];
}

extern "C" void kernel_launch(void* const* d_in, const int* in_sizes, int n_in,
                              void* d_out, int out_size, void* d_ws, size_t ws_size,
                              hipStream_t stream)
{
  const int*   src     = (const int*)  d_in[0];
  const int*   trg     = (const int*)  d_in[1];
  const int*   tf      = (const int*)  d_in[2];
  const float* enc_emb = (const float*)d_in[3];
  const float* dec_emb = (const float*)d_in[4];
  const float* Wih_e   = (const float*)d_in[5];
  const float* Whh_e   = (const float*)d_in[6];
  const float* b_e     = (const float*)d_in[7];
  const float* Wih_d   = (const float*)d_in[8];
  const float* Whh_d   = (const float*)d_in[9];
  const float* b_d     = (const float*)d_in[10];
  const float* Wfc     = (const float*)d_in[11];
  const float* bfc     = (const float*)d_in[12];
  float* out = (float*)d_out;
  float* ws  = (float*)d_ws;

  float* hbuf[2] = { ws,            ws + 65536 };
  float* cbuf[2] = { ws + 131072,   ws + 196608 };
  int*   tokbuf  = (int*)(ws + 262144);

  // zero h0/h1/c0/c1 (262144 floats) + out[:,0,:] (64*32000) = 2310144 elems = 9024*256
  k_init<<<9024, 256, 0, stream>>>(ws, out);

  int cur = 0;
  for (int t = 0; t < Sv; ++t){
    k_step<<<dim3(32,8), 256, 0, stream>>>(0, t, src, tf, tokbuf, enc_emb,
        Wih_e, Whh_e, b_e, hbuf[cur], cbuf[cur], hbuf[cur^1], cbuf[cur^1]);
    cur ^= 1;
  }
  for (int j = 0; j < Tv-1; ++j){
    k_step<<<dim3(32,8), 256, 0, stream>>>(1, j, trg, tf, tokbuf, dec_emb,
        Wih_d, Whh_d, b_d, hbuf[cur], cbuf[cur], hbuf[cur^1], cbuf[cur^1]);
    cur ^= 1;
    k_fc<<<1000, 256, 0, stream>>>(j, hbuf[cur], Wfc, bfc, out);
    if (j < Tv-2) k_argmax<<<64, 256, 0, stream>>>(j, out, tokbuf);
  }
}

// Round 2
// 16838.560 us; speedup vs baseline: 1.2132x; 1.2132x over previous
//
#include <hip/hip_runtime.h>
#include <math.h>

#define Hd 1024
#define Ed 512
#define Bv 64
#define Sv 128
#define Tv 64
#define Vv 32000

typedef __attribute__((ext_vector_type(8))) short bf16x8;
typedef __attribute__((ext_vector_type(4))) float f32x4;

__device__ __forceinline__ float sigf(float x){ return 1.0f/(1.0f + expf(-x)); }
__device__ __forceinline__ unsigned short f2bf(float f){
  unsigned u = __float_as_uint(f);
  return (unsigned short)((u + 0x7FFFu + ((u>>16)&1u)) >> 16);
}
__device__ __forceinline__ float bf2f(unsigned short b){ return __uint_as_float(((unsigned)b)<<16); }

// zero h/c ping-pong buffers (262144 floats) and out[:,0,:]
__global__ __launch_bounds__(256) void k_init(float* __restrict__ ws, float* __restrict__ out){
  long i = (long)blockIdx.x*256 + threadIdx.x;
  if (i < 262144){ ws[i] = 0.f; }
  else {
    long r = i - 262144;            // 0 .. 64*32000-1
    long m = r / Vv, v = r % Vv;
    out[m*Tv*(long)Vv + v] = 0.f;   // [m][0][v]
  }
}

// Fused LSTM step: gates = emb[token] @ Wih^T + h @ Whh^T + b ; cell -> h_out, c_out
// Epilogue also writes bf16 hi/lo split of h_out for the MFMA FC.
__global__ __launch_bounds__(256) void k_step(
    int mode, int t,
    const int* __restrict__ tok_src,      // src or trg
    const int* __restrict__ tf_mask,
    const int* __restrict__ token_buf,
    const float* __restrict__ emb,
    const float* __restrict__ Wih,        // [4096][512]
    const float* __restrict__ Whh,        // [4096][1024]
    const float* __restrict__ bias,       // [4096]
    const float* __restrict__ h_in, const float* __restrict__ c_in,
    float* __restrict__ h_out, float* __restrict__ c_out,
    unsigned short* __restrict__ hsp_hi, unsigned short* __restrict__ hsp_lo)
{
  __shared__ __align__(16) float tile[8*1536];  // per m-row: 512 x | 1024 h
  __shared__ float gbuf[4*8*32];
  __shared__ int toks[8];
  const int tid = threadIdx.x;
  const int m0 = blockIdx.y*8, jh0 = blockIdx.x*32;

  if (tid < 8){
    int m = m0 + tid; int tok;
    if (mode == 0) tok = tok_src[m*Sv + t];
    else {
      if (t == 0) tok = tok_src[m*Tv];
      else tok = (tf_mask[t] > 0) ? tok_src[m*Tv + t] : token_buf[m];
    }
    toks[tid] = tok;
  }
  __syncthreads();

  {
    float4* t4 = (float4*)tile;
    #pragma unroll
    for (int r = 0; r < 12; ++r){
      int f = tid + 256*r;          // 0..3071 float4s
      int row = f / 384, o = f % 384;
      float4 v;
      if (o < 128) v = ((const float4*)(emb + (long)toks[row]*Ed))[o];
      else         v = ((const float4*)(h_in + (long)(m0+row)*Hd))[o-128];
      t4[row*384 + o] = v;
    }
  }
  __syncthreads();

  const int g = tid >> 6, s = tid & 63, jl = s & 31, mg = s >> 5;
  const int col = g*Hd + jh0 + jl;
  const float4* wx = (const float4*)(Wih + (long)col*Ed);
  const float4* wh = (const float4*)(Whh + (long)col*Hd);
  const float4* t4 = (const float4*)tile;
  const int mb = mg*4;
  float b = bias[col];
  float a0=b, a1=b, a2=b, a3=b;

  for (int k = 0; k < 128; ++k){
    float4 w = wx[k];
    float4 v0 = t4[(mb+0)*384 + k];
    float4 v1 = t4[(mb+1)*384 + k];
    float4 v2 = t4[(mb+2)*384 + k];
    float4 v3 = t4[(mb+3)*384 + k];
    a0 += w.x*v0.x + w.y*v0.y + w.z*v0.z + w.w*v0.w;
    a1 += w.x*v1.x + w.y*v1.y + w.z*v1.z + w.w*v1.w;
    a2 += w.x*v2.x + w.y*v2.y + w.z*v2.z + w.w*v2.w;
    a3 += w.x*v3.x + w.y*v3.y + w.z*v3.z + w.w*v3.w;
  }
  for (int k = 0; k < 256; ++k){
    float4 w = wh[k];
    float4 v0 = t4[(mb+0)*384 + 128 + k];
    float4 v1 = t4[(mb+1)*384 + 128 + k];
    float4 v2 = t4[(mb+2)*384 + 128 + k];
    float4 v3 = t4[(mb+3)*384 + 128 + k];
    a0 += w.x*v0.x + w.y*v0.y + w.z*v0.z + w.w*v0.w;
    a1 += w.x*v1.x + w.y*v1.y + w.z*v1.z + w.w*v1.w;
    a2 += w.x*v2.x + w.y*v2.y + w.z*v2.z + w.w*v2.w;
    a3 += w.x*v3.x + w.y*v3.y + w.z*v3.z + w.w*v3.w;
  }

  gbuf[g*256 + (mb+0)*32 + jl] = a0;
  gbuf[g*256 + (mb+1)*32 + jl] = a1;
  gbuf[g*256 + (mb+2)*32 + jl] = a2;
  gbuf[g*256 + (mb+3)*32 + jl] = a3;
  __syncthreads();

  const int ml = tid >> 5, j2 = tid & 31;
  float ig = gbuf[0*256 + ml*32 + j2];
  float fg = gbuf[1*256 + ml*32 + j2];
  float gg = gbuf[2*256 + ml*32 + j2];
  float og = gbuf[3*256 + ml*32 + j2];
  long idx = (long)(m0+ml)*Hd + jh0 + j2;
  float c = c_in[idx];
  float cn = sigf(fg)*c + sigf(ig)*tanhf(gg);
  float hn = sigf(og)*tanhf(cn);
  c_out[idx] = cn;
  h_out[idx] = hn;
  unsigned short hh = f2bf(hn);
  hsp_hi[idx] = hh;
  hsp_lo[idx] = f2bf(hn - bf2f(hh));
}

// logits = h @ Wfc^T + bfc -> out[:, j+1, :]   (bf16x3 MFMA emulation of fp32)
// grid 500 blocks x 256 thr (4 waves); wave w: vocab cols [blk*64 + 16w, +16), all 64 m
__global__ __launch_bounds__(256) void k_fc(
    int j, const unsigned short* __restrict__ hhi, const unsigned short* __restrict__ hlo,
    const float* __restrict__ Wfc, const float* __restrict__ bfc, float* __restrict__ out)
{
  const int tid = threadIdx.x;
  const int wv = tid >> 6;
  const int lane = tid & 63;
  const int l15 = lane & 15, lk = lane >> 4;
  const int vcol = blockIdx.x*64 + wv*16 + l15;   // this lane's n (W row)
  const float* wrow = Wfc + (long)vcol*Hd;

  f32x4 acc[4];
  #pragma unroll
  for (int mt=0; mt<4; ++mt) acc[mt] = (f32x4){0.f,0.f,0.f,0.f};

  #pragma unroll 2
  for (int kt = 0; kt < 32; ++kt){
    const int k0 = kt*32 + lk*8;
    float4 wa = *(const float4*)(wrow + k0);
    float4 wb = *(const float4*)(wrow + k0 + 4);
    float wf[8] = {wa.x,wa.y,wa.z,wa.w,wb.x,wb.y,wb.z,wb.w};
    bf16x8 bh, bl;
    #pragma unroll
    for (int e=0;e<8;++e){
      unsigned short h = f2bf(wf[e]);
      bh[e] = (short)h;
      bl[e] = (short)f2bf(wf[e] - bf2f(h));
    }
    #pragma unroll
    for (int mt=0; mt<4; ++mt){
      const int row = mt*16 + l15;
      bf16x8 ah = *(const bf16x8*)(hhi + row*Hd + k0);
      bf16x8 al = *(const bf16x8*)(hlo + row*Hd + k0);
      acc[mt] = __builtin_amdgcn_mfma_f32_16x16x32_bf16(ah, bh, acc[mt], 0,0,0);
      acc[mt] = __builtin_amdgcn_mfma_f32_16x16x32_bf16(al, bh, acc[mt], 0,0,0);
      acc[mt] = __builtin_amdgcn_mfma_f32_16x16x32_bf16(ah, bl, acc[mt], 0,0,0);
    }
  }
  float bb = bfc[vcol];
  #pragma unroll
  for (int mt=0; mt<4; ++mt){
    #pragma unroll
    for (int r=0; r<4; ++r){
      int m = mt*16 + lk*4 + r;     // C/D: col=lane&15, row=(lane>>4)*4+reg
      out[((long)m*Tv + (j+1))*(long)Vv + vcol] = acc[mt][r] + bb;
    }
  }
}

// first-index argmax over out[m, j+1, :] -> token_buf[m]
__global__ __launch_bounds__(256) void k_argmax(
    int j, const float* __restrict__ out, int* __restrict__ token_buf)
{
  __shared__ float sval[256];
  __shared__ int   sidx[256];
  const int m = blockIdx.x, tid = threadIdx.x;
  const float* base = out + ((long)m*Tv + (j+1))*(long)Vv;
  float best = -INFINITY; int bi = 0;
  for (int v = tid; v < Vv; v += 256){
    float f = base[v];
    if (f > best){ best = f; bi = v; }
  }
  sval[tid] = best; sidx[tid] = bi;
  __syncthreads();
  for (int s2 = 128; s2 > 0; s2 >>= 1){
    if (tid < s2){
      float ov = sval[tid+s2]; int oi = sidx[tid+s2];
      if (ov > sval[tid] || (ov == sval[tid] && oi < sidx[tid])){
        sval[tid] = ov; sidx[tid] = oi;
      }
    }
    __syncthreads();
  }
  if (tid == 0) token_buf[m] = sidx[0];
}

extern "C" void kernel_launch(void* const* d_in, const int* in_sizes, int n_in,
                              void* d_out, int out_size, void* d_ws, size_t ws_size,
                              hipStream_t stream)
{
  const int*   src     = (const int*)  d_in[0];
  const int*   trg     = (const int*)  d_in[1];
  const int*   tf      = (const int*)  d_in[2];
  const float* enc_emb = (const float*)d_in[3];
  const float* dec_emb = (const float*)d_in[4];
  const float* Wih_e   = (const float*)d_in[5];
  const float* Whh_e   = (const float*)d_in[6];
  const float* b_e     = (const float*)d_in[7];
  const float* Wih_d   = (const float*)d_in[8];
  const float* Whh_d   = (const float*)d_in[9];
  const float* b_d     = (const float*)d_in[10];
  const float* Wfc     = (const float*)d_in[11];
  const float* bfc     = (const float*)d_in[12];
  float* out = (float*)d_out;
  float* ws  = (float*)d_ws;

  float* hbuf[2] = { ws,            ws + 65536 };
  float* cbuf[2] = { ws + 131072,   ws + 196608 };
  int*   tokbuf  = (int*)(ws + 262144);
  unsigned short* hsp_hi = (unsigned short*)(ws + 262208);           // [64][1024] bf16
  unsigned short* hsp_lo = (unsigned short*)(ws + 262208 + 32768);   // [64][1024] bf16

  // zero h0/h1/c0/c1 (262144 floats) + out[:,0,:] (64*32000) = 2310144 elems = 9024*256
  k_init<<<9024, 256, 0, stream>>>(ws, out);

  int cur = 0;
  for (int t = 0; t < Sv; ++t){
    k_step<<<dim3(32,8), 256, 0, stream>>>(0, t, src, tf, tokbuf, enc_emb,
        Wih_e, Whh_e, b_e, hbuf[cur], cbuf[cur], hbuf[cur^1], cbuf[cur^1], hsp_hi, hsp_lo);
    cur ^= 1;
  }
  for (int j = 0; j < Tv-1; ++j){
    k_step<<<dim3(32,8), 256, 0, stream>>>(1, j, trg, tf, tokbuf, dec_emb,
        Wih_d, Whh_d, b_d, hbuf[cur], cbuf[cur], hbuf[cur^1], cbuf[cur^1], hsp_hi, hsp_lo);
    cur ^= 1;
    k_fc<<<500, 256, 0, stream>>>(j, hsp_hi, hsp_lo, Wfc, bfc, out);
    if (j < Tv-2) k_argmax<<<64, 256, 0, stream>>>(j, out, tokbuf);
  }
}

// Round 4
// 16713.168 us; speedup vs baseline: 1.2223x; 1.0075x over previous
//
#include <hip/hip_runtime.h>
#include <math.h>

#define Hd 1024
#define Ed 512
#define Bv 64
#define Sv 128
#define Tv 64
#define Vv 32000

typedef __attribute__((ext_vector_type(8))) short bf16x8;
typedef __attribute__((ext_vector_type(4))) float f32x4;

__device__ __forceinline__ float sigf(float x){ return 1.0f/(1.0f + expf(-x)); }
__device__ __forceinline__ unsigned short f2bf(float f){
  unsigned u = __float_as_uint(f);
  return (unsigned short)((u + 0x7FFFu + ((u>>16)&1u)) >> 16);
}
__device__ __forceinline__ float bf2f(unsigned short b){ return __uint_as_float(((unsigned)b)<<16); }
// 3-way bf16 split: v = s0 + s1 + s2 + O(2^-24 v)
__device__ __forceinline__ void split3(float v, unsigned short& s0, unsigned short& s1, unsigned short& s2){
  s0 = f2bf(v);
  float r1 = v - bf2f(s0);
  s1 = f2bf(r1);
  s2 = f2bf(r1 - bf2f(s1));
}

// zero cbuf + all 6 H3 buffers (327680 floats) and out[:,0,:]
__global__ __launch_bounds__(256) void k_init(float* __restrict__ ws, float* __restrict__ out){
  long i = (long)blockIdx.x*256 + threadIdx.x;
  if (i < 327680){ ws[i] = 0.f; }
  else {
    long r = i - 327680;            // 0 .. 64*32000-1
    if (r < (long)Bv*Vv){
      long m = r / Vv, v = r % Vv;
      out[m*Tv*(long)Vv + v] = 0.f;   // [m][0][v]
    }
  }
}

// ---------------- weight pre-split kernels ----------------

// Wih[4096][512] | Whh[4096][1024] -> Wcat 3-way bf16 [4096][1536]
__global__ __launch_bounds__(256) void k_wsplit3(
    const float* __restrict__ Wih, const float* __restrict__ Whh,
    unsigned short* __restrict__ d0, unsigned short* __restrict__ d1, unsigned short* __restrict__ d2)
{
  const int row = blockIdx.x;
  const int tid = threadIdx.x;
  #pragma unroll
  for (int i = 0; i < 6; ++i){
    int e = tid + 256*i;
    float v = (e < 512) ? Wih[(long)row*512 + e] : Whh[(long)row*1024 + (e-512)];
    unsigned short s0,s1,s2; split3(v, s0,s1,s2);
    d0[(long)row*1536 + e] = s0;
    d1[(long)row*1536 + e] = s1;
    d2[(long)row*1536 + e] = s2;
  }
}

// Wfc[32000][1024] -> hi/lo bf16 (2-way, for bf16x3 FC)
__global__ __launch_bounds__(256) void k_fcsplit(
    const float* __restrict__ W, unsigned short* __restrict__ dhi, unsigned short* __restrict__ dlo)
{
  const int row = blockIdx.x;
  const int tid = threadIdx.x;
  #pragma unroll
  for (int i = 0; i < 4; ++i){
    int e = tid + 256*i;
    float v = W[(long)row*1024 + e];
    unsigned short h = f2bf(v);
    dhi[(long)row*1024 + e] = h;
    dlo[(long)row*1024 + e] = f2bf(v - bf2f(h));
  }
}

// gather+3-way-split encoder x for all steps [128][64][512], decoder x for j=0
__global__ __launch_bounds__(256) void k_prep_x3(
    const int* __restrict__ src, const int* __restrict__ trg,
    const float* __restrict__ enc_emb, const float* __restrict__ dec_emb,
    unsigned short* __restrict__ Xe0, unsigned short* __restrict__ Xe1, unsigned short* __restrict__ Xe2,
    unsigned short* __restrict__ Xd0, unsigned short* __restrict__ Xd1, unsigned short* __restrict__ Xd2)
{
  const int b = blockIdx.x, tid = threadIdx.x;
  const float* srow; long off;
  unsigned short *p0, *p1, *p2;
  if (b < 8192){
    int t = b >> 6, m = b & 63;
    int tok = src[m*Sv + t];
    srow = enc_emb + (long)tok*Ed;
    off = ((long)t*64 + m)*Ed;
    p0 = Xe0; p1 = Xe1; p2 = Xe2;
  } else {
    int m = b - 8192;
    int tok = trg[m*Tv];
    srow = dec_emb + (long)tok*Ed;
    off = (long)m*Ed;
    p0 = Xd0; p1 = Xd1; p2 = Xd2;
  }
  #pragma unroll
  for (int i = 0; i < 2; ++i){
    int e = tid + 256*i;
    unsigned short s0,s1,s2; split3(srow[e], s0,s1,s2);
    p0[off+e] = s0; p1[off+e] = s1; p2[off+e] = s2;
  }
}

// ---------------- MFMA LSTM step (bf16 3-way, 6-term emulation = fp32-exact) ----------------
// grid (64,2): x -> 16 hidden cols, y -> 32-row m half. 4 waves = 4 gates.
#define MF(A,B,C) __builtin_amdgcn_mfma_f32_16x16x32_bf16(A,B,C,0,0,0)
__global__ __launch_bounds__(256) void k_step2(
    const unsigned short* __restrict__ W0, const unsigned short* __restrict__ W1,
    const unsigned short* __restrict__ W2,                                          // [4096][1536]
    const float* __restrict__ bias,                                                 // [4096]
    const unsigned short* __restrict__ X0, const unsigned short* __restrict__ X1,
    const unsigned short* __restrict__ X2,                                          // [64][512]
    const unsigned short* __restrict__ H0in, const unsigned short* __restrict__ H1in,
    const unsigned short* __restrict__ H2in,                                        // [64][1024]
    const float* __restrict__ c_in,
    float* __restrict__ c_out,
    unsigned short* __restrict__ H0o, unsigned short* __restrict__ H1o,
    unsigned short* __restrict__ H2o)
{
  __shared__ float g4[4][32][16];
  const int tid = threadIdx.x;
  const int g = tid >> 6, lane = tid & 63;
  const int l15 = lane & 15, lk = lane >> 4;
  const int jh0 = blockIdx.x * 16;
  const int m0 = blockIdx.y * 32;
  const int n = g*Hd + jh0 + l15;
  const unsigned short* w0 = W0 + (long)n*1536;
  const unsigned short* w1 = W1 + (long)n*1536;
  const unsigned short* w2 = W2 + (long)n*1536;

  f32x4 acc0 = (f32x4){0.f,0.f,0.f,0.f};
  f32x4 acc1 = (f32x4){0.f,0.f,0.f,0.f};

  const long ra0x = (long)(m0 + l15)*Ed;
  const long ra1x = (long)(m0 + 16 + l15)*Ed;
  const long ra0h = (long)(m0 + l15)*Hd;
  const long ra1h = (long)(m0 + 16 + l15)*Hd;

  // x part: K = 0..511
  #pragma unroll 2
  for (int kt = 0; kt < 16; ++kt){
    const int k0 = kt*32 + lk*8;
    bf16x8 b0 = *(const bf16x8*)(w0 + k0);
    bf16x8 b1 = *(const bf16x8*)(w1 + k0);
    bf16x8 b2 = *(const bf16x8*)(w2 + k0);
    bf16x8 a00 = *(const bf16x8*)(X0 + ra0x + k0);
    bf16x8 a01 = *(const bf16x8*)(X1 + ra0x + k0);
    bf16x8 a02 = *(const bf16x8*)(X2 + ra0x + k0);
    bf16x8 a10 = *(const bf16x8*)(X0 + ra1x + k0);
    bf16x8 a11 = *(const bf16x8*)(X1 + ra1x + k0);
    bf16x8 a12 = *(const bf16x8*)(X2 + ra1x + k0);
    acc0 = MF(a00,b0,acc0); acc0 = MF(a01,b0,acc0); acc0 = MF(a00,b1,acc0);
    acc0 = MF(a02,b0,acc0); acc0 = MF(a00,b2,acc0); acc0 = MF(a01,b1,acc0);
    acc1 = MF(a10,b0,acc1); acc1 = MF(a11,b0,acc1); acc1 = MF(a10,b1,acc1);
    acc1 = MF(a12,b0,acc1); acc1 = MF(a10,b2,acc1); acc1 = MF(a11,b1,acc1);
  }
  // h part: K = 512..1535
  #pragma unroll 2
  for (int kt = 0; kt < 32; ++kt){
    const int kw = 512 + kt*32 + lk*8;
    const int ko = kt*32 + lk*8;
    bf16x8 b0 = *(const bf16x8*)(w0 + kw);
    bf16x8 b1 = *(const bf16x8*)(w1 + kw);
    bf16x8 b2 = *(const bf16x8*)(w2 + kw);
    bf16x8 a00 = *(const bf16x8*)(H0in + ra0h + ko);
    bf16x8 a01 = *(const bf16x8*)(H1in + ra0h + ko);
    bf16x8 a02 = *(const bf16x8*)(H2in + ra0h + ko);
    bf16x8 a10 = *(const bf16x8*)(H0in + ra1h + ko);
    bf16x8 a11 = *(const bf16x8*)(H1in + ra1h + ko);
    bf16x8 a12 = *(const bf16x8*)(H2in + ra1h + ko);
    acc0 = MF(a00,b0,acc0); acc0 = MF(a01,b0,acc0); acc0 = MF(a00,b1,acc0);
    acc0 = MF(a02,b0,acc0); acc0 = MF(a00,b2,acc0); acc0 = MF(a01,b1,acc0);
    acc1 = MF(a10,b0,acc1); acc1 = MF(a11,b0,acc1); acc1 = MF(a10,b1,acc1);
    acc1 = MF(a12,b0,acc1); acc1 = MF(a10,b2,acc1); acc1 = MF(a11,b1,acc1);
  }

  // C/D: col=lane&15, row=(lane>>4)*4+r
  #pragma unroll
  for (int r = 0; r < 4; ++r){
    g4[g][lk*4 + r][l15]      = acc0[r];
    g4[g][16 + lk*4 + r][l15] = acc1[r];
  }
  __syncthreads();

  #pragma unroll
  for (int rep = 0; rep < 2; ++rep){
    const int mloc = (tid >> 4) + rep*16;
    const int cl = tid & 15;
    const int col = jh0 + cl;
    float ig = g4[0][mloc][cl] + bias[0*Hd + col];
    float fg = g4[1][mloc][cl] + bias[1*Hd + col];
    float gg = g4[2][mloc][cl] + bias[2*Hd + col];
    float og = g4[3][mloc][cl] + bias[3*Hd + col];
    long idx = (long)(m0 + mloc)*Hd + col;
    float c = c_in[idx];
    float cn = sigf(fg)*c + sigf(ig)*tanhf(gg);
    float hn = sigf(og)*tanhf(cn);
    c_out[idx] = cn;
    unsigned short s0,s1,s2; split3(hn, s0,s1,s2);
    H0o[idx] = s0; H1o[idx] = s1; H2o[idx] = s2;
  }
}

// ---------------- MFMA FC, pre-split W (tier A) ----------------
__global__ __launch_bounds__(256) void k_fc2(
    int j,
    const unsigned short* __restrict__ hhi, const unsigned short* __restrict__ hlo,
    const unsigned short* __restrict__ Whi, const unsigned short* __restrict__ Wlo,
    const float* __restrict__ bfc, float* __restrict__ out)
{
  const int tid = threadIdx.x;
  const int wv = tid >> 6, lane = tid & 63;
  const int l15 = lane & 15, lk = lane >> 4;
  const int vbase = blockIdx.x*128 + wv*32;
  const int v0 = vbase + l15, v1 = vbase + 16 + l15;
  const unsigned short* w0h = Whi + (long)v0*Hd;
  const unsigned short* w0l = Wlo + (long)v0*Hd;
  const unsigned short* w1h = Whi + (long)v1*Hd;
  const unsigned short* w1l = Wlo + (long)v1*Hd;

  f32x4 acc[2][4];
  #pragma unroll
  for (int nv=0; nv<2; ++nv)
    #pragma unroll
    for (int mt=0; mt<4; ++mt) acc[nv][mt] = (f32x4){0.f,0.f,0.f,0.f};

  #pragma unroll 2
  for (int kt = 0; kt < 32; ++kt){
    const int k0 = kt*32 + lk*8;
    bf16x8 b0h = *(const bf16x8*)(w0h + k0);
    bf16x8 b0l = *(const bf16x8*)(w0l + k0);
    bf16x8 b1h = *(const bf16x8*)(w1h + k0);
    bf16x8 b1l = *(const bf16x8*)(w1l + k0);
    #pragma unroll
    for (int mt=0; mt<4; ++mt){
      const int row = mt*16 + l15;
      bf16x8 ah = *(const bf16x8*)(hhi + (long)row*Hd + k0);
      bf16x8 al = *(const bf16x8*)(hlo + (long)row*Hd + k0);
      acc[0][mt] = MF(ah, b0h, acc[0][mt]);
      acc[0][mt] = MF(al, b0h, acc[0][mt]);
      acc[0][mt] = MF(ah, b0l, acc[0][mt]);
      acc[1][mt] = MF(ah, b1h, acc[1][mt]);
      acc[1][mt] = MF(al, b1h, acc[1][mt]);
      acc[1][mt] = MF(ah, b1l, acc[1][mt]);
    }
  }
  float bb0 = bfc[v0], bb1 = bfc[v1];
  #pragma unroll
  for (int mt=0; mt<4; ++mt){
    #pragma unroll
    for (int r=0; r<4; ++r){
      int m = mt*16 + lk*4 + r;
      out[((long)m*Tv + (j+1))*(long)Vv + v0] = acc[0][mt][r] + bb0;
      out[((long)m*Tv + (j+1))*(long)Vv + v1] = acc[1][mt][r] + bb1;
    }
  }
}

// ---------------- MFMA FC, in-register split (tier B, round-2 proven) ----------------
__global__ __launch_bounds__(256) void k_fc(
    int j, const unsigned short* __restrict__ hhi, const unsigned short* __restrict__ hlo,
    const float* __restrict__ Wfc, const float* __restrict__ bfc, float* __restrict__ out)
{
  const int tid = threadIdx.x;
  const int wv = tid >> 6, lane = tid & 63;
  const int l15 = lane & 15, lk = lane >> 4;
  const int vcol = blockIdx.x*64 + wv*16 + l15;
  const float* wrow = Wfc + (long)vcol*Hd;
  f32x4 acc[4];
  #pragma unroll
  for (int mt=0; mt<4; ++mt) acc[mt] = (f32x4){0.f,0.f,0.f,0.f};
  #pragma unroll 2
  for (int kt = 0; kt < 32; ++kt){
    const int k0 = kt*32 + lk*8;
    float4 wa = *(const float4*)(wrow + k0);
    float4 wb = *(const float4*)(wrow + k0 + 4);
    float wf[8] = {wa.x,wa.y,wa.z,wa.w,wb.x,wb.y,wb.z,wb.w};
    bf16x8 bh, bl;
    #pragma unroll
    for (int e=0;e<8;++e){
      unsigned short h = f2bf(wf[e]);
      bh[e] = (short)h; bl[e] = (short)f2bf(wf[e] - bf2f(h));
    }
    #pragma unroll
    for (int mt=0; mt<4; ++mt){
      const int row = mt*16 + l15;
      bf16x8 ah = *(const bf16x8*)(hhi + (long)row*Hd + k0);
      bf16x8 al = *(const bf16x8*)(hlo + (long)row*Hd + k0);
      acc[mt] = MF(ah, bh, acc[mt]);
      acc[mt] = MF(al, bh, acc[mt]);
      acc[mt] = MF(ah, bl, acc[mt]);
    }
  }
  float bb = bfc[vcol];
  #pragma unroll
  for (int mt=0; mt<4; ++mt)
    #pragma unroll
    for (int r=0; r<4; ++r){
      int m = mt*16 + lk*4 + r;
      out[((long)m*Tv + (j+1))*(long)Vv + vcol] = acc[mt][r] + bb;
    }
}

// argmax over out[m, j+1, :] fused with next-x gather + 3-way split
__global__ __launch_bounds__(256) void k_argmax3(
    int j, const float* __restrict__ out,
    const int* __restrict__ tf_mask, const int* __restrict__ trg,
    const float* __restrict__ dec_emb,
    unsigned short* __restrict__ Xd0, unsigned short* __restrict__ Xd1,
    unsigned short* __restrict__ Xd2)
{
  __shared__ float sval[256];
  __shared__ int   sidx[256];
  const int m = blockIdx.x, tid = threadIdx.x;
  const float* base = out + ((long)m*Tv + (j+1))*(long)Vv;
  float best = -INFINITY; int bi = 0;
  for (int v = tid; v < Vv; v += 256){
    float f = base[v];
    if (f > best){ best = f; bi = v; }
  }
  sval[tid] = best; sidx[tid] = bi;
  __syncthreads();
  for (int s2 = 128; s2 > 0; s2 >>= 1){
    if (tid < s2){
      float ov = sval[tid+s2]; int oi = sidx[tid+s2];
      if (ov > sval[tid] || (ov == sval[tid] && oi < sidx[tid])){
        sval[tid] = ov; sidx[tid] = oi;
      }
    }
    __syncthreads();
  }
  int nxt = (tf_mask[j+1] > 0) ? trg[m*Tv + (j+1)] : sidx[0];
  const float* srow = dec_emb + (long)nxt*Ed;
  #pragma unroll
  for (int i = 0; i < 2; ++i){
    int e = tid + 256*i;
    unsigned short s0,s1,s2; split3(srow[e], s0,s1,s2);
    Xd0[(long)m*Ed + e] = s0;
    Xd1[(long)m*Ed + e] = s1;
    Xd2[(long)m*Ed + e] = s2;
  }
}

// ---------------- round-2 full fallback (tier C) ----------------

__global__ __launch_bounds__(256) void k_initC(float* __restrict__ ws, float* __restrict__ out){
  long i = (long)blockIdx.x*256 + threadIdx.x;
  if (i < 262144){ ws[i] = 0.f; }
  else {
    long r = i - 262144;
    long m = r / Vv, v = r % Vv;
    out[m*Tv*(long)Vv + v] = 0.f;
  }
}

__global__ __launch_bounds__(256) void k_stepC(
    int mode, int t,
    const int* __restrict__ tok_src, const int* __restrict__ tf_mask,
    const int* __restrict__ token_buf, const float* __restrict__ emb,
    const float* __restrict__ Wih, const float* __restrict__ Whh,
    const float* __restrict__ bias,
    const float* __restrict__ h_in, const float* __restrict__ c_in,
    float* __restrict__ h_out, float* __restrict__ c_out,
    unsigned short* __restrict__ hsp_hi, unsigned short* __restrict__ hsp_lo)
{
  __shared__ __align__(16) float tile[8*1536];
  __shared__ float gbuf[4*8*32];
  __shared__ int toks[8];
  const int tid = threadIdx.x;
  const int m0 = blockIdx.y*8, jh0 = blockIdx.x*32;
  if (tid < 8){
    int m = m0 + tid; int tok;
    if (mode == 0) tok = tok_src[m*Sv + t];
    else { if (t == 0) tok = tok_src[m*Tv];
           else tok = (tf_mask[t] > 0) ? tok_src[m*Tv + t] : token_buf[m]; }
    toks[tid] = tok;
  }
  __syncthreads();
  { float4* t4 = (float4*)tile;
    #pragma unroll
    for (int r = 0; r < 12; ++r){
      int f = tid + 256*r; int row = f / 384, o = f % 384; float4 v;
      if (o < 128) v = ((const float4*)(emb + (long)toks[row]*Ed))[o];
      else         v = ((const float4*)(h_in + (long)(m0+row)*Hd))[o-128];
      t4[row*384 + o] = v; } }
  __syncthreads();
  const int g = tid >> 6, s = tid & 63, jl = s & 31, mg = s >> 5;
  const int col = g*Hd + jh0 + jl;
  const float4* wx = (const float4*)(Wih + (long)col*Ed);
  const float4* wh = (const float4*)(Whh + (long)col*Hd);
  const float4* t4 = (const float4*)tile;
  const int mb = mg*4;
  float b = bias[col];
  float a0=b, a1=b, a2=b, a3=b;
  for (int k = 0; k < 128; ++k){
    float4 w = wx[k];
    float4 v0 = t4[(mb+0)*384 + k]; float4 v1 = t4[(mb+1)*384 + k];
    float4 v2 = t4[(mb+2)*384 + k]; float4 v3 = t4[(mb+3)*384 + k];
    a0 += w.x*v0.x + w.y*v0.y + w.z*v0.z + w.w*v0.w;
    a1 += w.x*v1.x + w.y*v1.y + w.z*v1.z + w.w*v1.w;
    a2 += w.x*v2.x + w.y*v2.y + w.z*v2.z + w.w*v2.w;
    a3 += w.x*v3.x + w.y*v3.y + w.z*v3.z + w.w*v3.w;
  }
  for (int k = 0; k < 256; ++k){
    float4 w = wh[k];
    float4 v0 = t4[(mb+0)*384 + 128 + k]; float4 v1 = t4[(mb+1)*384 + 128 + k];
    float4 v2 = t4[(mb+2)*384 + 128 + k]; float4 v3 = t4[(mb+3)*384 + 128 + k];
    a0 += w.x*v0.x + w.y*v0.y + w.z*v0.z + w.w*v0.w;
    a1 += w.x*v1.x + w.y*v1.y + w.z*v1.z + w.w*v1.w;
    a2 += w.x*v2.x + w.y*v2.y + w.z*v2.z + w.w*v2.w;
    a3 += w.x*v3.x + w.y*v3.y + w.z*v3.z + w.w*v3.w;
  }
  gbuf[g*256 + (mb+0)*32 + jl] = a0; gbuf[g*256 + (mb+1)*32 + jl] = a1;
  gbuf[g*256 + (mb+2)*32 + jl] = a2; gbuf[g*256 + (mb+3)*32 + jl] = a3;
  __syncthreads();
  const int ml = tid >> 5, j2 = tid & 31;
  float ig = gbuf[0*256 + ml*32 + j2];
  float fg = gbuf[1*256 + ml*32 + j2];
  float gg = gbuf[2*256 + ml*32 + j2];
  float og = gbuf[3*256 + ml*32 + j2];
  long idx = (long)(m0+ml)*Hd + jh0 + j2;
  float c = c_in[idx];
  float cn = sigf(fg)*c + sigf(ig)*tanhf(gg);
  float hn = sigf(og)*tanhf(cn);
  c_out[idx] = cn; h_out[idx] = hn;
  unsigned short hh = f2bf(hn);
  hsp_hi[idx] = hh; hsp_lo[idx] = f2bf(hn - bf2f(hh));
}

__global__ __launch_bounds__(256) void k_argmaxC(
    int j, const float* __restrict__ out, int* __restrict__ token_buf)
{
  __shared__ float sval[256];
  __shared__ int   sidx[256];
  const int m = blockIdx.x, tid = threadIdx.x;
  const float* base = out + ((long)m*Tv + (j+1))*(long)Vv;
  float best = -INFINITY; int bi = 0;
  for (int v = tid; v < Vv; v += 256){
    float f = base[v];
    if (f > best){ best = f; bi = v; }
  }
  sval[tid] = best; sidx[tid] = bi;
  __syncthreads();
  for (int s2 = 128; s2 > 0; s2 >>= 1){
    if (tid < s2){
      float ov = sval[tid+s2]; int oi = sidx[tid+s2];
      if (ov > sval[tid] || (ov == sval[tid] && oi < sidx[tid])){
        sval[tid] = ov; sidx[tid] = oi;
      }
    }
    __syncthreads();
  }
  if (tid == 0) token_buf[m] = sidx[0];
}

extern "C" void kernel_launch(void* const* d_in, const int* in_sizes, int n_in,
                              void* d_out, int out_size, void* d_ws, size_t ws_size,
                              hipStream_t stream)
{
  const int*   src     = (const int*)  d_in[0];
  const int*   trg     = (const int*)  d_in[1];
  const int*   tf      = (const int*)  d_in[2];
  const float* enc_emb = (const float*)d_in[3];
  const float* dec_emb = (const float*)d_in[4];
  const float* Wih_e   = (const float*)d_in[5];
  const float* Whh_e   = (const float*)d_in[6];
  const float* b_e     = (const float*)d_in[7];
  const float* Wih_d   = (const float*)d_in[8];
  const float* Whh_d   = (const float*)d_in[9];
  const float* b_d     = (const float*)d_in[10];
  const float* Wfc     = (const float*)d_in[11];
  const float* bfc     = (const float*)d_in[12];
  float* out = (float*)d_out;
  float* ws  = (float*)d_ws;

  const size_t NEED_A = 58310656ULL * 4ULL;   // ~233.2 MB (with pre-split Wfc)
  const size_t NEED_B = 25542656ULL * 4ULL;   // ~102.2 MB (in-register-split FC)

  if (ws_size >= NEED_B){
    const bool presplit_fc = (ws_size >= NEED_A);
    // ---- layout (float offsets) ----
    float* cbuf[2] = { ws, ws + 65536 };
    unsigned short* HB = (unsigned short*)(ws + 131072);
    unsigned short* H0[2] = { HB,          HB + 65536 };
    unsigned short* H1[2] = { HB + 131072, HB + 196608 };
    unsigned short* H2[2] = { HB + 262144, HB + 327680 };
    unsigned short* XD = (unsigned short*)(ws + 327680);
    unsigned short *Xd0 = XD, *Xd1 = XD + 32768, *Xd2 = XD + 65536;
    unsigned short* XE = (unsigned short*)(ws + 376832);
    unsigned short *Xe0 = XE, *Xe1 = XE + 4194304, *Xe2 = XE + 8388608;
    unsigned short* WE = (unsigned short*)(ws + 6668288);
    unsigned short *We0 = WE, *We1 = WE + 6291456, *We2 = WE + 12582912;
    unsigned short* WD = (unsigned short*)(ws + 16105472);
    unsigned short *Wd0 = WD, *Wd1 = WD + 6291456, *Wd2 = WD + 12582912;
    unsigned short* WF = (unsigned short*)(ws + 25542656);
    unsigned short *Wf_hi = WF, *Wf_lo = WF + 32768000;

    // zero cbuf+H3 (327680 fl) + out[:,0,:] (2048000) = 2375680 = 9280*256
    k_init<<<9280, 256, 0, stream>>>(ws, out);
    k_wsplit3<<<4096, 256, 0, stream>>>(Wih_e, Whh_e, We0, We1, We2);
    k_wsplit3<<<4096, 256, 0, stream>>>(Wih_d, Whh_d, Wd0, Wd1, Wd2);
    if (presplit_fc) k_fcsplit<<<32000, 256, 0, stream>>>(Wfc, Wf_hi, Wf_lo);
    k_prep_x3<<<8256, 256, 0, stream>>>(src, trg, enc_emb, dec_emb,
                                        Xe0, Xe1, Xe2, Xd0, Xd1, Xd2);

    int cur = 0;
    for (int t = 0; t < Sv; ++t){
      k_step2<<<dim3(64,2), 256, 0, stream>>>(We0, We1, We2, b_e,
          Xe0 + (long)t*32768, Xe1 + (long)t*32768, Xe2 + (long)t*32768,
          H0[cur], H1[cur], H2[cur], cbuf[cur],
          cbuf[cur^1], H0[cur^1], H1[cur^1], H2[cur^1]);
      cur ^= 1;
    }
    for (int j = 0; j < Tv-1; ++j){
      k_step2<<<dim3(64,2), 256, 0, stream>>>(Wd0, Wd1, Wd2, b_d,
          Xd0, Xd1, Xd2,
          H0[cur], H1[cur], H2[cur], cbuf[cur],
          cbuf[cur^1], H0[cur^1], H1[cur^1], H2[cur^1]);
      cur ^= 1;
      if (presplit_fc)
        k_fc2<<<250, 256, 0, stream>>>(j, H0[cur], H1[cur], Wf_hi, Wf_lo, bfc, out);
      else
        k_fc<<<500, 256, 0, stream>>>(j, H0[cur], H1[cur], Wfc, bfc, out);
      if (j < Tv-2)
        k_argmax3<<<64, 256, 0, stream>>>(j, out, tf, trg, dec_emb, Xd0, Xd1, Xd2);
    }
  } else {
    // ---- tier C: round-2 fallback ----
    float* hbuf[2] = { ws,            ws + 65536 };
    float* cbuf[2] = { ws + 131072,   ws + 196608 };
    int*   tokbuf  = (int*)(ws + 262144);
    unsigned short* hsp_hi = (unsigned short*)(ws + 262208);
    unsigned short* hsp_lo = (unsigned short*)(ws + 262208 + 32768);

    k_initC<<<9024, 256, 0, stream>>>(ws, out);
    int cur = 0;
    for (int t = 0; t < Sv; ++t){
      k_stepC<<<dim3(32,8), 256, 0, stream>>>(0, t, src, tf, tokbuf, enc_emb,
          Wih_e, Whh_e, b_e, hbuf[cur], cbuf[cur], hbuf[cur^1], cbuf[cur^1], hsp_hi, hsp_lo);
      cur ^= 1;
    }
    for (int j = 0; j < Tv-1; ++j){
      k_stepC<<<dim3(32,8), 256, 0, stream>>>(1, j, trg, tf, tokbuf, dec_emb,
          Wih_d, Whh_d, b_d, hbuf[cur], cbuf[cur], hbuf[cur^1], cbuf[cur^1], hsp_hi, hsp_lo);
      cur ^= 1;
      k_fc<<<500, 256, 0, stream>>>(j, hsp_hi, hsp_lo, Wfc, bfc, out);
      if (j < Tv-2) k_argmaxC<<<64, 256, 0, stream>>>(j, out, tokbuf);
    }
  }
}